// Round 6
// baseline (170.802 us; speedup 1.0000x reference)
//
#include <hip/hip_runtime.h>
#include <hip/hip_bf16.h>

#define BN 8192      // batch rows
#define MM 8199      // real rows (BN + 7 centers)
#define MP 8208      // padded to multiple of 16
#define HH 128       // feature dim
#define EE 256       // center embedding dim
#define GX 128       // i-blocks (64 rows each)
#define GY 16
#define NUM_HIST 7

typedef __attribute__((ext_vector_type(8))) short short8;   // 8 bf16 = 4 VGPRs
typedef __attribute__((ext_vector_type(4))) float floatx4;

// ---- prep kernel: fuses {zero tot/pos, centers GEMV, row-normalize, labp}
// blocks 0..2047: 4 batch rows each (wave per row) + zero 8 floats of tot/pos.
// block 2048: curr_centers into LDS, then normalize the 16 padded rows.
__global__ __launch_bounds__(256)
void prep_kernel(const float* __restrict__ reps,
                 const int* __restrict__ labels,
                 const float* __restrict__ centers,
                 const float* __restrict__ fc_w,
                 const float* __restrict__ fc_b,
                 __hip_bfloat16* __restrict__ rn,
                 int* __restrict__ labp,
                 float* __restrict__ tot) {  // pos = tot + BN (contiguous)
  const int wid = threadIdx.x >> 6, lane = threadIdx.x & 63;
  const int b = blockIdx.x;
  if (b < 2048) {
    if (threadIdx.x < 8) tot[b * 8 + threadIdx.x] = 0.f;   // zeroes tot+pos (16384 floats)
    const int r = b * 4 + wid;
    float2 v = ((const float2*)(reps + (size_t)r * HH))[lane];
    float ss = v.x * v.x + v.y * v.y;
#pragma unroll
    for (int m = 1; m < 64; m <<= 1) ss += __shfl_xor(ss, m);
    float inv = 1.0f / fmaxf(sqrtf(ss), 1e-8f);
    __hip_bfloat162 h2;
    h2.x = __float2bfloat16(v.x * inv);
    h2.y = __float2bfloat16(v.y * inv);
    ((__hip_bfloat162*)(rn + (size_t)r * HH))[lane] = h2;
    if (lane == 0) labp[r] = labels[r];
  } else {
    // ---- block 2048: centers @ fc_w^T + fc_b  -> LDS, then padded rows
    __shared__ float currs[7 * HH];
    for (int o = threadIdx.x; o < 7 * HH; o += 256) {
      int c = o >> 7, h = o & 127;
      const float4* ce = (const float4*)(centers + c * EE);
      const float4* w  = (const float4*)(fc_w + h * EE);
      float s = 0.f;
#pragma unroll 4
      for (int j = 0; j < EE / 4; ++j) {
        float4 a = ce[j], bb = w[j];
        s += a.x * bb.x + a.y * bb.y + a.z * bb.z + a.w * bb.w;
      }
      currs[o] = s + fc_b[h];
    }
    __syncthreads();
    // rows 8192..8207: wave wid handles 4 rows
    for (int k = 0; k < 4; ++k) {
      int c = wid * 4 + k;            // 0..15
      int r = BN + c;
      float2 v = make_float2(0.f, 0.f);
      if (c < 7) v = ((const float2*)(currs + c * HH))[lane];
      float ss = v.x * v.x + v.y * v.y;
#pragma unroll
      for (int m = 1; m < 64; m <<= 1) ss += __shfl_xor(ss, m);
      float inv = 1.0f / fmaxf(sqrtf(ss), 1e-8f);
      __hip_bfloat162 h2;
      h2.x = __float2bfloat16(v.x * inv);
      h2.y = __float2bfloat16(v.y * inv);
      ((__hip_bfloat162*)(rn + (size_t)r * HH))[lane] = h2;
      if (lane == 0) labp[r] = (r < MM) ? r - BN : -1;
    }
  }
}

// ---- main kernel: per i-row, tot_i = sum_j e_ij (j!=i), pos_i = same over label match
// e_ij = exp2((cos_ij - 1) * (0.5/TEMP) * log2e)   [global-max shift cancels in ratio]
// Padded j-columns (rn==0) contribute exactly exp2(-K2) each to tot; the loss
// kernel subtracts the exact constant 9*exp2(-K2). Padded labp=-1 never matches.
//
// r5 diagnosis: dur invariant to occupancy (r4) AND to VALU count (r5) while all
// pipes <30% busy -> exposed per-iteration load latency is the critical path.
// Fix: contiguous 8-tile chunk per wave, fully-unrolled 4-pair software pipeline
// with register double-buffering: next pair's 8 dwordx4 loads issue BEFORE the
// current pair's MFMA+epilogue, so latency hides under ~600cyc of compute.
// Tile 512 (rows 8192..8207, never diagonal) is chunk 63's predicated tail.
// j-labels preloaded (8 regs) to keep the loop free of scalar-load chains.
//
// NOTE: NO __threadfence() anywhere — agent fences on gfx950 emit buffer_wbl2+
// buffer_inv (whole-L2 ops); 2048 of them tripled this kernel's duration (r3).
// NOTE: launch_bounds min-waves MUST stay <=2 — (256,5) forced VGPR=48 and
// spilled afrag to scratch (FETCH 410MB, 3x slowdown). This version needs ~210.
__global__ __launch_bounds__(256, 2)
void main_kernel(const __hip_bfloat16* __restrict__ rn,
                 const int* __restrict__ labp,
                 float* __restrict__ tot,
                 float* __restrict__ pos) {
  __shared__ float red[128];   // [0..63]=tot for i-rows, [64..127]=pos
  const int lane = threadIdx.x & 63;
  const int wid  = threadIdx.x >> 6;
  const int q = lane >> 4, col = lane & 15;
  const int ibase = blockIdx.x * 64;
  const int chunk = (blockIdx.y << 2) | wid;   // 0..63, owns rows [chunk*128, chunk*128+128)
  const int jrow0 = chunk * 128;
  const short* rns = (const short*)rn;

  if (threadIdx.x < 128) red[threadIdx.x] = 0.f;

  // A fragments: lane holds A[m=col][k = kk*32 + q*8 + 0..7]
  short8 afrag[4][4];
#pragma unroll
  for (int it = 0; it < 4; ++it) {
    const short8* p = (const short8*)(rns + (size_t)(ibase + it * 16 + col) * HH + q * 8);
    afrag[it][0] = p[0];
    afrag[it][1] = p[4];
    afrag[it][2] = p[8];
    afrag[it][3] = p[12];
  }
  // i-labels for C/D layout rows: row = q*4 + r
  int labi[4][4];
#pragma unroll
  for (int it = 0; it < 4; ++it)
#pragma unroll
    for (int r = 0; r < 4; ++r)
      labi[it][r] = labp[ibase + it * 16 + q * 4 + r];

  // preload the 8 j-labels (one per tile) — removes scalar loads from the loop
  int labj[8];
#pragma unroll
  for (int t = 0; t < 8; ++t) labj[t] = labp[jrow0 + t * 16 + col];

  float stot[4][4] = {};
  float spos[4][4] = {};
  const float K2 = 10.30496147f;  // 0.5/0.07 * log2(e)

  const short* jbase = rns + (size_t)(jrow0 + col) * HH + q * 8;

  // compute one 64x16 tile against B fragments bfr[0..3]
  auto compute_tile = [&](const short8* bfr, int labjv, int jb) {
#pragma unroll
    for (int it = 0; it < 4; ++it) {
      floatx4 acc = {0.f, 0.f, 0.f, 0.f};
      acc = __builtin_amdgcn_mfma_f32_16x16x32_bf16(afrag[it][0], bfr[0], acc, 0, 0, 0);
      acc = __builtin_amdgcn_mfma_f32_16x16x32_bf16(afrag[it][1], bfr[1], acc, 0, 0, 0);
      acc = __builtin_amdgcn_mfma_f32_16x16x32_bf16(afrag[it][2], bfr[2], acc, 0, 0, 0);
      acc = __builtin_amdgcn_mfma_f32_16x16x32_bf16(afrag[it][3], bfr[3], acc, 0, 0, 0);
      const bool isdiag = (jb == ibase + it * 16);  // wave-uniform
#pragma unroll
      for (int r = 0; r < 4; ++r) {
        // C/D layout: row = q*4 + r, col = lane&15 → i = ibase+it*16+q*4+r, j = jb+col
        float e = __builtin_amdgcn_exp2f(fmaf(acc[r], K2, -K2));  // raw v_exp_f32
        if (isdiag && (col == q * 4 + r)) e = 0.f;   // exclude diagonal j==i
        stot[it][r] += e;
        spos[it][r] += (labjv == labi[it][r]) ? e : 0.f;
      }
    }
  };

  short8 bufA[2][4], bufB[2][4];
  // prologue: load pair 0 (tiles 0,1)
#pragma unroll
  for (int u = 0; u < 2; ++u) {
    const short8* p = (const short8*)(jbase + (size_t)(u * 16) * HH);
    bufA[u][0] = p[0]; bufA[u][1] = p[4]; bufA[u][2] = p[8]; bufA[u][3] = p[12];
  }

#pragma unroll
  for (int pr = 0; pr < 4; ++pr) {
    short8 (*cur)[4] = (pr & 1) ? bufB : bufA;
    short8 (*nxt)[4] = (pr & 1) ? bufA : bufB;
    if (pr < 3) {
      // issue next pair's 8 independent dwordx4 loads BEFORE computing current
#pragma unroll
      for (int u = 0; u < 2; ++u) {
        const short8* p = (const short8*)(jbase + (size_t)((pr * 2 + 2 + u) * 16) * HH);
        nxt[u][0] = p[0]; nxt[u][1] = p[4]; nxt[u][2] = p[8]; nxt[u][3] = p[12];
      }
    }
#pragma unroll
    for (int u = 0; u < 2; ++u) {
      const int t = pr * 2 + u;
      compute_tile(cur[u], labj[t], jrow0 + t * 16);
    }
  }

  // tail: chunk 63 also owns tile 512 (rows 8192..8207; jb=8192 > any i → no diag)
  if (chunk == 63) {
    const short8* p = (const short8*)(rns + (size_t)(8192 + col) * HH + q * 8);
    short8 tb[4];
    tb[0] = p[0]; tb[1] = p[4]; tb[2] = p[8]; tb[3] = p[12];
    int lj = labp[8192 + col];
    compute_tile(tb, lj, 8192);
  }

  __syncthreads();   // red[] init visible

  // reduce across the 16 column-lanes, then across waves via LDS,
  // then ONE global atomic per i-row per block.
#pragma unroll
  for (int it = 0; it < 4; ++it)
#pragma unroll
    for (int r = 0; r < 4; ++r) {
      float tt = stot[it][r], pp = spos[it][r];
#pragma unroll
      for (int m = 1; m <= 8; m <<= 1) {
        tt += __shfl_xor(tt, m);
        pp += __shfl_xor(pp, m);
      }
      if (col == 0) {
        int li = it * 16 + q * 4 + r;   // 0..63 local i-row
        atomicAdd(&red[li], tt);
        atomicAdd(&red[64 + li], pp);
      }
    }
  __syncthreads();
  if (threadIdx.x < 64)       atomicAdd(&tot[ibase + threadIdx.x], red[threadIdx.x]);
  else if (threadIdx.x < 128) atomicAdd(&pos[ibase + threadIdx.x - 64], red[threadIdx.x]);
}

// ---- loss kernel: loss = sum(lv * (lv>0.3)) / (sum(lv>0.3) + eps),
//      lv = -log( ((pos/(tot-9*epad))/(hist[lab]+eps)) + eps )
__global__ __launch_bounds__(1024)
void loss_kernel(const float* __restrict__ tot,
                 const float* __restrict__ pos,
                 const int* __restrict__ labels,
                 float* __restrict__ out) {
  __shared__ int hist[NUM_HIST];
  __shared__ float s1[16], s2[16];
  const int tid = threadIdx.x;
  const int lane = tid & 63, wid = tid >> 6;
  if (tid < NUM_HIST) hist[tid] = 0;
  __syncthreads();
  // ballot-based histogram: 7 ballots per 1024-element stripe, no LDS contention
  int c0 = 0, c1 = 0, c2 = 0, c3 = 0, c4 = 0, c5 = 0, c6 = 0;
  for (int i = tid; i < BN; i += 1024) {
    int lab = labels[i];
    unsigned long long m0 = __ballot(lab == 0);
    unsigned long long m1 = __ballot(lab == 1);
    unsigned long long m2 = __ballot(lab == 2);
    unsigned long long m3 = __ballot(lab == 3);
    unsigned long long m4 = __ballot(lab == 4);
    unsigned long long m5 = __ballot(lab == 5);
    unsigned long long m6 = __ballot(lab == 6);
    if (lane == 0) {
      c0 += __popcll(m0); c1 += __popcll(m1); c2 += __popcll(m2);
      c3 += __popcll(m3); c4 += __popcll(m4); c5 += __popcll(m5);
      c6 += __popcll(m6);
    }
  }
  if (lane == 0) {
    atomicAdd(&hist[0], c0); atomicAdd(&hist[1], c1); atomicAdd(&hist[2], c2);
    atomicAdd(&hist[3], c3); atomicAdd(&hist[4], c4); atomicAdd(&hist[5], c5);
    atomicAdd(&hist[6], c6);
  }
  __syncthreads();
  const float K2 = 10.30496147f;
  const float epad9 = 9.0f * exp2f(-K2);   // padded-column excess in tot
  float lsum = 0.f, msum = 0.f;
  for (int i = tid; i < BN; i += 1024) {
    float t = tot[i] - epad9;
    float p = pos[i];
    float c = (float)hist[labels[i]];   // = sum(pos_mask*mask) exactly
    float pr = (p / t) / (c + 1e-8f);
    float lv = -logf(pr + 1e-8f);
    if (lv > 0.3f) { lsum += lv; msum += 1.f; }
  }
#pragma unroll
  for (int m = 1; m < 64; m <<= 1) {
    lsum += __shfl_xor(lsum, m);
    msum += __shfl_xor(msum, m);
  }
  if (lane == 0) { s1[wid] = lsum; s2[wid] = msum; }
  __syncthreads();
  if (wid == 0) {
    float a = (lane < 16) ? s1[lane] : 0.f;
    float b = (lane < 16) ? s2[lane] : 0.f;
#pragma unroll
    for (int m = 1; m < 16; m <<= 1) {
      a += __shfl_xor(a, m);
      b += __shfl_xor(b, m);
    }
    if (lane == 0) out[0] = a / (b + 1e-8f);
  }
}

extern "C" void kernel_launch(void* const* d_in, const int* in_sizes, int n_in,
                              void* d_out, int out_size, void* d_ws, size_t ws_size,
                              hipStream_t stream) {
  const float* reps    = (const float*)d_in[0];  // [8192,128]
  const int*   labels  = (const int*)d_in[1];    // [8192]
  const float* centers = (const float*)d_in[2];  // [7,256]
  const float* fc_w    = (const float*)d_in[3];  // [128,256]
  const float* fc_b    = (const float*)d_in[4];  // [128]
  float* out = (float*)d_out;

  char* ws = (char*)d_ws;
  int* labp   = (int*)(ws + 4096);                       // 8208*4
  __hip_bfloat16* rn = (__hip_bfloat16*)(ws + 40960);    // 8208*128*2 = 2101248 B
  float* tot = (float*)(ws + 40960 + 2101248);           // 8192*4
  float* pos = tot + BN;                                 // 8192*4 (contiguous after tot)

  prep_kernel<<<2049, 256, 0, stream>>>(reps, labels, centers, fc_w, fc_b, rn, labp, tot);
  main_kernel<<<dim3(GX, GY), 256, 0, stream>>>(rn, labp, tot, pos);
  loss_kernel<<<1, 1024, 0, stream>>>(tot, pos, labels, out);
}

// Round 7
// 143.057 us; speedup vs baseline: 1.1939x; 1.1939x over previous
//
#include <hip/hip_runtime.h>
#include <hip/hip_bf16.h>

#define BN 8192      // batch rows
#define MM 8199      // real rows (BN + 7 centers)
#define MP 8208      // padded to multiple of 16
#define HH 128       // feature dim
#define EE 256       // center embedding dim
#define GX 128       // i-blocks (64 rows each)
#define GY 16
#define NUM_HIST 7

typedef __attribute__((ext_vector_type(8))) short short8;   // 8 bf16 = 4 VGPRs
typedef __attribute__((ext_vector_type(4))) float floatx4;

// ============================================================================
// TRANSPOSED LAYOUT rnt: MFMA-fragment-order so every main_kernel load is a
// contiguous 1KB per wave.  For j-tile t (16 rows), k-block kblk (8 bf16),
// col (row-within-tile):  bf16 addr = t*2048 + kblk*128 + col*8.
// A wave's fragment kk load: rnt + t*2048 + kk*512 + lane*8  (lane=q*16+col,
// q*128+col*8 == lane*8)  -> lanes cover [0,1024) bytes contiguously.
// r0-r6 lesson: the old row-major layout made every dwordx4 touch 16 rows at
// 256B stride (64B used per 128B line); measured VMEM ceiling ~6 TB/s across
// FOUR structurally different kernels (occupancy x2, VALU -40%, SW pipeline
// all null). Coalescing the pattern is the only lever left.
// ============================================================================

// ---- prep kernel: fuses {zero tot/pos, centers GEMV, row-normalize+transpose}
// blocks 0..2047: 4 batch rows each (wave per row) + zero 8 floats of tot/pos.
// block 2048: curr_centers into LDS, then the 16 padded rows (zeros for c>=7).
__global__ __launch_bounds__(256)
void prep_kernel(const float* __restrict__ reps,
                 const int* __restrict__ labels,
                 const float* __restrict__ centers,
                 const float* __restrict__ fc_w,
                 const float* __restrict__ fc_b,
                 __hip_bfloat16* __restrict__ rnt,
                 int* __restrict__ labp,
                 float* __restrict__ tot) {  // pos = tot + BN (contiguous)
  const int wid = threadIdx.x >> 6, lane = threadIdx.x & 63;
  const int b = blockIdx.x;
  if (b < 2048) {
    if (threadIdx.x < 8) tot[b * 8 + threadIdx.x] = 0.f;   // zeroes tot+pos (16384 floats)
    const int r = b * 4 + wid;
    float2 v = ((const float2*)(reps + (size_t)r * HH))[lane];   // k = 2*lane, 2*lane+1
    float ss = v.x * v.x + v.y * v.y;
#pragma unroll
    for (int m = 1; m < 64; m <<= 1) ss += __shfl_xor(ss, m);
    float inv = 1.0f / fmaxf(sqrtf(ss), 1e-8f);
    __hip_bfloat162 h2;
    h2.x = __float2bfloat16(v.x * inv);
    h2.y = __float2bfloat16(v.y * inv);
    // transposed store: bf16 addr = (r>>4)*2048 + (lane>>2)*128 + (r&15)*8 + 2*(lane&3)
    size_t o = (size_t)(r >> 4) * 1024 + (lane >> 2) * 64 + (r & 15) * 4 + (lane & 3);
    ((__hip_bfloat162*)rnt)[o] = h2;
    if (lane == 0) labp[r] = labels[r];
  } else {
    // ---- block 2048: centers @ fc_w^T + fc_b  -> LDS, then padded rows
    __shared__ float currs[7 * HH];
    for (int o = threadIdx.x; o < 7 * HH; o += 256) {
      int c = o >> 7, h = o & 127;
      const float4* ce = (const float4*)(centers + c * EE);
      const float4* w  = (const float4*)(fc_w + h * EE);
      float s = 0.f;
#pragma unroll 4
      for (int j = 0; j < EE / 4; ++j) {
        float4 a = ce[j], bb = w[j];
        s += a.x * bb.x + a.y * bb.y + a.z * bb.z + a.w * bb.w;
      }
      currs[o] = s + fc_b[h];
    }
    __syncthreads();
    // rows 8192..8207 (j-tile 512): wave wid handles 4 rows; zeros for c>=7
    for (int k = 0; k < 4; ++k) {
      int c = wid * 4 + k;            // 0..15
      int r = BN + c;
      float2 v = make_float2(0.f, 0.f);
      if (c < 7) v = ((const float2*)(currs + c * HH))[lane];
      float ss = v.x * v.x + v.y * v.y;
#pragma unroll
      for (int m = 1; m < 64; m <<= 1) ss += __shfl_xor(ss, m);
      float inv = 1.0f / fmaxf(sqrtf(ss), 1e-8f);
      __hip_bfloat162 h2;
      h2.x = __float2bfloat16(v.x * inv);
      h2.y = __float2bfloat16(v.y * inv);
      size_t o = (size_t)(r >> 4) * 1024 + (lane >> 2) * 64 + (r & 15) * 4 + (lane & 3);
      ((__hip_bfloat162*)rnt)[o] = h2;
      if (lane == 0) labp[r] = (r < MM) ? r - BN : -1;
    }
  }
}

// ---- main kernel: per i-row, tot_i = sum_j e_ij (j!=i), pos_i = same over label match
// e_ij = exp2((cos_ij - 1) * (0.5/TEMP) * log2e)   [global-max shift cancels in ratio]
// Padded j-columns (rnt==0) contribute exactly exp2(-K2) each to tot; the loss
// kernel subtracts the exact constant 9*exp2(-K2). Padded labp=-1 never matches.
// Structure = round-5 measured form (64 i-rows/block, strided chunks, builtin
// exp2); ONLY the load addressing changed (transposed layout, coalesced 1KB).
// NOTE: NO __threadfence() anywhere — agent fences on gfx950 emit buffer_wbl2+
// buffer_inv (whole-L2 ops); 2048 of them tripled this kernel's duration (r3).
// NOTE: launch_bounds min-waves MUST stay <=2 — (256,5) forced VGPR=48 and
// spilled afrag to scratch (FETCH 410MB, 3x slowdown).
__global__ __launch_bounds__(256, 2)
void main_kernel(const __hip_bfloat16* __restrict__ rnt,
                 const int* __restrict__ labp,
                 float* __restrict__ tot,
                 float* __restrict__ pos) {
  __shared__ float red[128];   // [0..63]=tot for i-rows, [64..127]=pos
  const int lane = threadIdx.x & 63;
  const int wid  = threadIdx.x >> 6;
  const int q = lane >> 4, col = lane & 15;
  const int ibase = blockIdx.x * 64;
  const int chunk = (blockIdx.y << 2) | wid;   // 0..63
  const short* rns = (const short*)rnt;

  if (threadIdx.x < 128) red[threadIdx.x] = 0.f;

  // A fragments: lane holds A[m=col][k = kk*32 + q*8 + 0..7]
  // tile (blockIdx.x*4 + it), coalesced: base + kk*512 + lane*8
  short8 afrag[4][4];
#pragma unroll
  for (int it = 0; it < 4; ++it) {
    const short* base = rns + (size_t)(blockIdx.x * 4 + it) * 2048 + lane * 8;
    afrag[it][0] = *(const short8*)(base);
    afrag[it][1] = *(const short8*)(base + 512);
    afrag[it][2] = *(const short8*)(base + 1024);
    afrag[it][3] = *(const short8*)(base + 1536);
  }
  // i-labels for C/D layout rows: row = q*4 + r
  int labi[4][4];
#pragma unroll
  for (int it = 0; it < 4; ++it)
#pragma unroll
    for (int r = 0; r < 4; ++r)
      labi[it][r] = labp[ibase + it * 16 + q * 4 + r];

  float stot[4][4] = {};
  float spos[4][4] = {};
  const float K2 = 10.30496147f;  // 0.5/0.07 * log2(e)

  // B tiles: chunk strides 64 tiles (=131072 shorts) per step
  const short* bptr = rns + (size_t)chunk * 2048 + lane * 8;
  const int* lptr = labp + chunk * 16 + col;

  for (int jb = chunk * 16; jb < MP; jb += 1024) {
    // B fragments: lane holds B[k = kk*32 + q*8 + 0..7][n=col] — coalesced 1KB each
    short8 b0 = *(const short8*)(bptr);
    short8 b1 = *(const short8*)(bptr + 512);
    short8 b2 = *(const short8*)(bptr + 1024);
    short8 b3 = *(const short8*)(bptr + 1536);
    const int labj = *lptr;
    bptr += 64 * 2048;
    lptr += 1024;
#pragma unroll
    for (int it = 0; it < 4; ++it) {
      floatx4 acc = {0.f, 0.f, 0.f, 0.f};
      acc = __builtin_amdgcn_mfma_f32_16x16x32_bf16(afrag[it][0], b0, acc, 0, 0, 0);
      acc = __builtin_amdgcn_mfma_f32_16x16x32_bf16(afrag[it][1], b1, acc, 0, 0, 0);
      acc = __builtin_amdgcn_mfma_f32_16x16x32_bf16(afrag[it][2], b2, acc, 0, 0, 0);
      acc = __builtin_amdgcn_mfma_f32_16x16x32_bf16(afrag[it][3], b3, acc, 0, 0, 0);
      const bool isdiag = (jb == ibase + it * 16);  // wave-uniform
#pragma unroll
      for (int r = 0; r < 4; ++r) {
        // C/D layout: row = q*4 + r, col = lane&15 → i = ibase+it*16+q*4+r, j = jb+col
        float e = __builtin_amdgcn_exp2f(fmaf(acc[r], K2, -K2));  // raw v_exp_f32
        if (isdiag && (col == q * 4 + r)) e = 0.f;   // exclude diagonal j==i
        stot[it][r] += e;
        spos[it][r] += (labj == labi[it][r]) ? e : 0.f;
      }
    }
  }

  __syncthreads();   // red[] init visible

  // reduce across the 16 column-lanes, then across waves via LDS,
  // then ONE global atomic per i-row per block.
#pragma unroll
  for (int it = 0; it < 4; ++it)
#pragma unroll
    for (int r = 0; r < 4; ++r) {
      float tt = stot[it][r], pp = spos[it][r];
#pragma unroll
      for (int m = 1; m <= 8; m <<= 1) {
        tt += __shfl_xor(tt, m);
        pp += __shfl_xor(pp, m);
      }
      if (col == 0) {
        int li = it * 16 + q * 4 + r;   // 0..63 local i-row
        atomicAdd(&red[li], tt);
        atomicAdd(&red[64 + li], pp);
      }
    }
  __syncthreads();
  if (threadIdx.x < 64)       atomicAdd(&tot[ibase + threadIdx.x], red[threadIdx.x]);
  else if (threadIdx.x < 128) atomicAdd(&pos[ibase + threadIdx.x - 64], red[threadIdx.x]);
}

// ---- loss kernel: loss = sum(lv * (lv>0.3)) / (sum(lv>0.3) + eps),
//      lv = -log( ((pos/(tot-9*epad))/(hist[lab]+eps)) + eps )
__global__ __launch_bounds__(1024)
void loss_kernel(const float* __restrict__ tot,
                 const float* __restrict__ pos,
                 const int* __restrict__ labels,
                 float* __restrict__ out) {
  __shared__ int hist[NUM_HIST];
  __shared__ float s1[16], s2[16];
  const int tid = threadIdx.x;
  const int lane = tid & 63, wid = tid >> 6;
  if (tid < NUM_HIST) hist[tid] = 0;
  __syncthreads();
  // ballot-based histogram: 7 ballots per 1024-element stripe, no LDS contention
  int c0 = 0, c1 = 0, c2 = 0, c3 = 0, c4 = 0, c5 = 0, c6 = 0;
  for (int i = tid; i < BN; i += 1024) {
    int lab = labels[i];
    unsigned long long m0 = __ballot(lab == 0);
    unsigned long long m1 = __ballot(lab == 1);
    unsigned long long m2 = __ballot(lab == 2);
    unsigned long long m3 = __ballot(lab == 3);
    unsigned long long m4 = __ballot(lab == 4);
    unsigned long long m5 = __ballot(lab == 5);
    unsigned long long m6 = __ballot(lab == 6);
    if (lane == 0) {
      c0 += __popcll(m0); c1 += __popcll(m1); c2 += __popcll(m2);
      c3 += __popcll(m3); c4 += __popcll(m4); c5 += __popcll(m5);
      c6 += __popcll(m6);
    }
  }
  if (lane == 0) {
    atomicAdd(&hist[0], c0); atomicAdd(&hist[1], c1); atomicAdd(&hist[2], c2);
    atomicAdd(&hist[3], c3); atomicAdd(&hist[4], c4); atomicAdd(&hist[5], c5);
    atomicAdd(&hist[6], c6);
  }
  __syncthreads();
  const float K2 = 10.30496147f;
  const float epad9 = 9.0f * exp2f(-K2);   // padded-column excess in tot
  float lsum = 0.f, msum = 0.f;
  for (int i = tid; i < BN; i += 1024) {
    float t = tot[i] - epad9;
    float p = pos[i];
    float c = (float)hist[labels[i]];   // = sum(pos_mask*mask) exactly
    float pr = (p / t) / (c + 1e-8f);
    float lv = -logf(pr + 1e-8f);
    if (lv > 0.3f) { lsum += lv; msum += 1.f; }
  }
#pragma unroll
  for (int m = 1; m < 64; m <<= 1) {
    lsum += __shfl_xor(lsum, m);
    msum += __shfl_xor(msum, m);
  }
  if (lane == 0) { s1[wid] = lsum; s2[wid] = msum; }
  __syncthreads();
  if (wid == 0) {
    float a = (lane < 16) ? s1[lane] : 0.f;
    float b = (lane < 16) ? s2[lane] : 0.f;
#pragma unroll
    for (int m = 1; m < 16; m <<= 1) {
      a += __shfl_xor(a, m);
      b += __shfl_xor(b, m);
    }
    if (lane == 0) out[0] = a / (b + 1e-8f);
  }
}

extern "C" void kernel_launch(void* const* d_in, const int* in_sizes, int n_in,
                              void* d_out, int out_size, void* d_ws, size_t ws_size,
                              hipStream_t stream) {
  const float* reps    = (const float*)d_in[0];  // [8192,128]
  const int*   labels  = (const int*)d_in[1];    // [8192]
  const float* centers = (const float*)d_in[2];  // [7,256]
  const float* fc_w    = (const float*)d_in[3];  // [128,256]
  const float* fc_b    = (const float*)d_in[4];  // [128]
  float* out = (float*)d_out;

  char* ws = (char*)d_ws;
  int* labp   = (int*)(ws + 4096);                       // 8208*4
  __hip_bfloat16* rnt = (__hip_bfloat16*)(ws + 40960);   // 513 tiles * 4KB = 2101248 B
  float* tot = (float*)(ws + 40960 + 2101248);           // 8192*4
  float* pos = tot + BN;                                 // 8192*4 (contiguous after tot)

  prep_kernel<<<2049, 256, 0, stream>>>(reps, labels, centers, fc_w, fc_b, rnt, labp, tot);
  main_kernel<<<dim3(GX, GY), 256, 0, stream>>>(rnt, labp, tot, pos);
  loss_kernel<<<1, 1024, 0, stream>>>(tot, pos, labels, out);
}